// Round 4
// baseline (1367.572 us; speedup 1.0000x reference)
//
#include <hip/hip_runtime.h>
#include <stdint.h>

// ---------------- common helpers ----------------

typedef __attribute__((ext_vector_type(8))) short frag8;   // 8 bf16 (4 VGPRs), MFMA A/B operand
typedef __attribute__((ext_vector_type(4))) float frag4f;  // 4 fp32, MFMA C/D operand

__device__ __forceinline__ uint16_t f2bf(float f) {
  union { float f; uint32_t i; } x; x.f = f;
  uint32_t r = x.i + 0x7fffu + ((x.i >> 16) & 1u);  // round-to-nearest-even
  return (uint16_t)(r >> 16);
}

// ---------------- kernel 0: fp32 -> bf16 conversion (RTNE), vectorized ----------------

__global__ __launch_bounds__(256)
void k_cvt(const float* __restrict__ src, uint16_t* __restrict__ dst, int n4, int ok)
{
  if (!ok) return;
  int i = blockIdx.x * 256 + threadIdx.x;
  const int stride = gridDim.x * 256;
  for (; i < n4; i += stride) {
    float4 v = ((const float4*)src)[i];
    ushort4 o;
    o.x = f2bf(v.x); o.y = f2bf(v.y); o.z = f2bf(v.z); o.w = f2bf(v.w);
    ((ushort4*)dst)[i] = o;
  }
}

// ---------------- kernel 1: fused roll + QKV GEMM + windowed attention ----------------
// grid: 512 M-tiles (128 rows = 8 batches) x 16 heads = 8192 blocks, 256 threads.
// Inputs: bf16 copies of x / w_qkv in ws; fp32 b_qkv / rel_pos direct.
// Output: bf16 attn (65536 x 1024) written into d_out's bytes (exact fit).

struct SmemGemm { uint16_t A[128 * 32]; uint16_t B[192 * 32]; };              // 8 KB + 12 KB
struct SmemEpi  { uint16_t q[128][72]; uint16_t k[128][72];                    // 18 KB x2
                  uint16_t vT[64][136]; uint16_t p[8][16][24]; };              // 17 KB + 6 KB
union Smem1 { SmemGemm s; SmemEpi e; };                                        // 59 KB -> 2 blocks/CU

__global__ __launch_bounds__(256, 2)
void k_qkv_attn(const uint16_t* __restrict__ xb, const uint16_t* __restrict__ wqkvb,
                const float* __restrict__ b_qkv, const float* __restrict__ rel_pos,
                uint16_t* __restrict__ attn16, int ws_ok)
{
  __shared__ Smem1 sm;
  const int bid  = blockIdx.x;
  const int h    = bid & 15;
  const int mt   = bid >> 4;
  const int t    = threadIdx.x;
  const int lane = t & 63;
  const int wv   = t >> 6;
  const int l15  = lane & 15;
  const int quad = lane >> 4;
  const int wr   = wv & 1;
  const int wc   = wv >> 1;

  if (!ws_ok) {  // ws too small: write zero attn slice (diagnostic), touch no ws
    #pragma unroll
    for (int i = 0; i < 32; ++i) {
      const int local = t + 256 * i;           // 0..8191
      const int row = local >> 6, col = local & 63;
      attn16[(mt * 128 + row) * 1024 + h * 64 + col] = 0;
    }
    return;
  }

  // A staging: roll(-8 tokens within each batch of 16) folded into source row.
  const int arow0 = t >> 2, aoff = t & 3;
  const int g0 = mt * 128 + arow0;
  const int g1 = g0 + 64;
  const int asrc0 = (((g0 & ~15) | ((g0 + 8) & 15)) * 512) + aoff * 8;
  const int asrc1 = (((g1 & ~15) | ((g1 + 8) & 15)) * 512) + aoff * 8;
  int bsrc[3];
  #pragma unroll
  for (int i = 0; i < 3; ++i) {
    int c = t + 256 * i;
    int brow = c >> 2;  // 0..191
    int gc = (brow < 64) ? (h * 64 + brow)
           : (brow < 128) ? (1024 + h * 64 + (brow - 64))
                          : (2048 + h * 64 + (brow - 128));
    bsrc[i] = gc * 512 + (c & 3) * 8;
  }

  frag4f acc[4][6];
  #pragma unroll
  for (int a = 0; a < 4; ++a)
    #pragma unroll
    for (int b = 0; b < 6; ++b) acc[a][b] = (frag4f)0.0f;

  for (int kk = 0; kk < 16; ++kk) {
    const int kb = kk * 32;
    uint4 va0 = *(const uint4*)(xb + asrc0 + kb);
    uint4 va1 = *(const uint4*)(xb + asrc1 + kb);
    uint4 vb0 = *(const uint4*)(wqkvb + bsrc[0] + kb);
    uint4 vb1 = *(const uint4*)(wqkvb + bsrc[1] + kb);
    uint4 vb2 = *(const uint4*)(wqkvb + bsrc[2] + kb);
    __syncthreads();
    *(uint4*)&sm.s.A[t * 8]         = va0;
    *(uint4*)&sm.s.A[(t + 256) * 8] = va1;
    *(uint4*)&sm.s.B[t * 8]         = vb0;
    *(uint4*)&sm.s.B[(t + 256) * 8] = vb1;
    *(uint4*)&sm.s.B[(t + 512) * 8] = vb2;
    __syncthreads();
    frag8 af[4], bf[6];
    #pragma unroll
    for (int rt = 0; rt < 4; ++rt)
      af[rt] = *(const frag8*)&sm.s.A[(wr * 64 + rt * 16 + l15) * 32 + quad * 8];
    #pragma unroll
    for (int ct = 0; ct < 6; ++ct)
      bf[ct] = *(const frag8*)&sm.s.B[((wc * 6 + ct) * 16 + l15) * 32 + quad * 8];
    #pragma unroll
    for (int rt = 0; rt < 4; ++rt)
      #pragma unroll
      for (int ct = 0; ct < 6; ++ct)
        acc[rt][ct] = __builtin_amdgcn_mfma_f32_16x16x32_bf16(af[rt], bf[ct], acc[rt][ct], 0, 0, 0);
  }
  __syncthreads();  // staging LDS dead; epilogue aliases it

  // ---- epilogue: +bias (fp32), stage Q, K row-major and V transposed ----
  #pragma unroll
  for (int ct = 0; ct < 6; ++ct) {
    const int C = (wc * 6 + ct) * 16 + l15;  // 0..191
    const int gc = (C < 64) ? (h * 64 + C)
                 : (C < 128) ? (1024 + h * 64 + (C - 64))
                             : (2048 + h * 64 + (C - 128));
    const float bias = b_qkv[gc];
    #pragma unroll
    for (int rt = 0; rt < 4; ++rt) {
      #pragma unroll
      for (int r = 0; r < 4; ++r) {
        const int row = wr * 64 + rt * 16 + quad * 4 + r;  // C-layout: row=quad*4+reg, col=l15
        const uint16_t val = f2bf(acc[rt][ct][r] + bias);
        if (C < 64)       sm.e.q[row][C] = val;
        else if (C < 128) sm.e.k[row][C - 64] = val;
        else              sm.e.vT[C - 128][row] = val;
      }
    }
  }
  __syncthreads();

  // ---- attention: wave wv handles windows {2wv, 2wv+1} ----
  const float scl = 0.125f;  // 64^-0.5
  #pragma unroll
  for (int bbi = 0; bbi < 2; ++bbi) {
    const int bb = wv * 2 + bbi;
    frag8 a0 = *(const frag8*)&sm.e.q[bb * 16 + l15][quad * 8];
    frag8 a1 = *(const frag8*)&sm.e.q[bb * 16 + l15][32 + quad * 8];
    frag8 b0 = *(const frag8*)&sm.e.k[bb * 16 + l15][quad * 8];
    frag8 b1 = *(const frag8*)&sm.e.k[bb * 16 + l15][32 + quad * 8];
    frag4f s = (frag4f)0.0f;
    s = __builtin_amdgcn_mfma_f32_16x16x32_bf16(a0, b0, s, 0, 0, 0);
    s = __builtin_amdgcn_mfma_f32_16x16x32_bf16(a1, b1, s, 0, 0, 0);
    const int j = l15;
    #pragma unroll
    for (int r = 0; r < 4; ++r) {
      const int i = quad * 4 + r;
      const int r0 = (i >> 2) - (j >> 2) + 3;
      const int r1 = (i & 3) - (j & 3) + 3;
      const float bias = rel_pos[h * 49 + r0 * 7 + r1];
      const bool msk = ((h >= 14) && (((i >> 2) < 2) != ((j >> 2) < 2))) ||
                       ((h & 1)  && (((i & 3) < 2) != ((j & 3) < 2)));
      float v = msk ? -1e30f : (s[r] * scl + bias);
      float m = v;
      m = fmaxf(m, __shfl_xor(m, 1));
      m = fmaxf(m, __shfl_xor(m, 2));
      m = fmaxf(m, __shfl_xor(m, 4));
      m = fmaxf(m, __shfl_xor(m, 8));
      float e = __expf(v - m);
      float su = e;
      su += __shfl_xor(su, 1);
      su += __shfl_xor(su, 2);
      su += __shfl_xor(su, 4);
      su += __shfl_xor(su, 8);
      sm.e.p[bb][i][j] = f2bf(e / su);
    }
  }
  __syncthreads();

  // ---- O = P V; K=32 MFMA with k>=16 half of A zeroed ----
  #pragma unroll
  for (int bbi = 0; bbi < 2; ++bbi) {
    const int bb = wv * 2 + bbi;
    frag8 ap;
    if (quad < 2) ap = *(const frag8*)&sm.e.p[bb][l15][quad * 8];
    else          ap = (frag8)0;
    #pragma unroll
    for (int dt = 0; dt < 4; ++dt) {
      frag8 bv = *(const frag8*)&sm.e.vT[dt * 16 + l15][bb * 16 + (quad & 1) * 8];
      frag4f o = (frag4f)0.0f;
      o = __builtin_amdgcn_mfma_f32_16x16x32_bf16(ap, bv, o, 0, 0, 0);
      #pragma unroll
      for (int r = 0; r < 4; ++r) {
        const int grow = mt * 128 + bb * 16 + quad * 4 + r;
        attn16[grow * 1024 + h * 64 + dt * 16 + l15] = f2bf(o[r]);
      }
    }
  }
}

// ---------------- kernel 2: projection GEMM (M=65536, K=1024, N=512) + bias, fp32 out ----------------
// grid: 2048 blocks, tile = 32 rows x all 512 cols. A (bf16) read from d_out's
// bytes; each block reads ONLY its own 32 rows, then overwrites exactly those
// rows with fp32 -> no inter-block race (row r: 1024 bf16 = 512 fp32 = 2048 B).

struct Smem2 { uint16_t A[32 * 40]; uint16_t B[512 * 40]; };  // 2.5 KB + 40 KB

__global__ __launch_bounds__(256, 2)
void k_proj(const uint16_t* __restrict__ attn16, const uint16_t* __restrict__ wprojb,
            const float* __restrict__ b_proj, float* __restrict__ out, int ws_ok)
{
  __shared__ Smem2 sm;
  const int mt   = blockIdx.x;      // 0..2047
  const int t    = threadIdx.x;
  const int lane = t & 63;
  const int wv   = t >> 6;
  const int l15  = lane & 15;
  const int quad = lane >> 4;
  const int rb   = wv & 1;          // row block (16 rows)
  const int ch   = wv >> 1;         // col half (256 cols)

  frag4f acc[16];
  #pragma unroll
  for (int i = 0; i < 16; ++i) acc[i] = (frag4f)0.0f;

  for (int kk = 0; kk < 32; ++kk) {
    const int kglob = kk * 32;
    uint4 va = {0, 0, 0, 0};
    int arow = 0, ako = 0;
    if (t < 128) {
      arow = t >> 2; ako = (t & 3) * 8;
      va = *(const uint4*)(attn16 + (mt * 32 + arow) * 1024 + kglob + ako);
    }
    uint4 vb[8] = {};
    if (ws_ok) {
      #pragma unroll
      for (int i = 0; i < 8; ++i) {
        const int c2 = t + 256 * i;
        vb[i] = *(const uint4*)(wprojb + (c2 >> 2) * 1024 + kglob + (c2 & 3) * 8);
      }
    }
    __syncthreads();
    if (t < 128) *(uint4*)&sm.A[arow * 40 + ako] = va;
    #pragma unroll
    for (int i = 0; i < 8; ++i) {
      const int c2 = t + 256 * i;
      *(uint4*)&sm.B[(c2 >> 2) * 40 + (c2 & 3) * 8] = vb[i];
    }
    __syncthreads();
    frag8 af = *(const frag8*)&sm.A[(rb * 16 + l15) * 40 + quad * 8];
    #pragma unroll
    for (int ct = 0; ct < 16; ++ct) {
      frag8 bf = *(const frag8*)&sm.B[(ch * 256 + ct * 16 + l15) * 40 + quad * 8];
      acc[ct] = __builtin_amdgcn_mfma_f32_16x16x32_bf16(af, bf, acc[ct], 0, 0, 0);
    }
  }

  #pragma unroll
  for (int ct = 0; ct < 16; ++ct) {
    const int gc = ch * 256 + ct * 16 + l15;
    const float bias = b_proj[gc];
    #pragma unroll
    for (int r = 0; r < 4; ++r) {
      const int grow = mt * 32 + rb * 16 + quad * 4 + r;
      out[grow * 512 + gc] = acc[ct][r] + bias;
    }
  }
}

// ---------------- launch ----------------

extern "C" void kernel_launch(void* const* d_in, const int* in_sizes, int n_in,
                              void* d_out, int out_size, void* d_ws, size_t ws_size,
                              hipStream_t stream) {
  const float* x      = (const float*)d_in[0];   // (4096,16,512) fp32
  const float* w_qkv  = (const float*)d_in[1];   // (3072,512)    fp32
  const float* b_qkv  = (const float*)d_in[2];   // (3072,)       fp32
  const float* w_proj = (const float*)d_in[3];   // (512,1024)    fp32
  const float* b_proj = (const float*)d_in[4];   // (512,)        fp32
  const float* rel    = (const float*)d_in[5];   // (16,7,7)      fp32

  // ws layout (bf16): x 33,554,432 | w_qkv 1,572,864 | w_proj 524,288 el
  uint16_t* xb     = (uint16_t*)d_ws;
  uint16_t* wqkvb  = xb + 33554432;
  uint16_t* wprojb = wqkvb + 1572864;
  const size_t ws_need = (size_t)(33554432 + 1572864 + 524288) * 2;
  const int ws_ok = (ws_size >= ws_need) ? 1 : 0;

  // d_out bytes: phase 1 = bf16 attn (65536 x 1024 x 2B), phase 2 = fp32 out (65536 x 512 x 4B)
  uint16_t* attn16 = (uint16_t*)d_out;
  float*    out    = (float*)d_out;

  k_cvt<<<dim3(4096), dim3(256), 0, stream>>>(x,      xb,     33554432 / 4, ws_ok);
  k_cvt<<<dim3(1536), dim3(256), 0, stream>>>(w_qkv,  wqkvb,  1572864 / 4,  ws_ok);
  k_cvt<<<dim3(512),  dim3(256), 0, stream>>>(w_proj, wprojb, 524288 / 4,   ws_ok);
  k_qkv_attn<<<dim3(512 * 16), dim3(256), 0, stream>>>(xb, wqkvb, b_qkv, rel, attn16, ws_ok);
  k_proj   <<<dim3(2048),     dim3(256), 0, stream>>>(attn16, wprojb, b_proj, out, ws_ok);
}